// Round 1
// baseline (190.040 us; speedup 1.0000x reference)
//
#include <hip/hip_runtime.h>

#define B_SZ   4096
#define H_SZ   200
#define D_SZ   128
#define N_SZ   256
#define ROWS   (B_SZ * H_SZ)      // 819200
#define BM     64
#define NTILES (ROWS / BM)        // 12800
#define NBLK   512
#define TPB    (NTILES / NBLK)    // 25

typedef __attribute__((ext_vector_type(8))) short bf16x8;
typedef __attribute__((ext_vector_type(4))) float f32x4;

__device__ __forceinline__ unsigned short f2bf(float f) {
    unsigned u = __builtin_bit_cast(unsigned, f);
    u += 0x7FFFu + ((u >> 16) & 1u);          // round-to-nearest-even
    return (unsigned short)(u >> 16);
}

// Kernel A: a[r] = w2 . relu(X[r,:] @ W1 + b1),  dotd[r] = sum_d X[r,d]
// where X[r,d] = embed_history[history[r]][d] * embed_target[target[r/H]][d]
__global__ __launch_bounds__(256, 2) void nais_main(
    const int* __restrict__ history, const int* __restrict__ target,
    const float* __restrict__ eh, const float* __restrict__ et,
    const float* __restrict__ W1, const float* __restrict__ b1,
    const float* __restrict__ w2,
    float* __restrict__ a_out, float* __restrict__ dotd_out)
{
    __shared__ uint4 AbufV[BM * 256 / 16];    // 16 KB: [64 rows][128 bf16], XOR-swizzled
    __shared__ float apart[4][BM];
    char* Abuf = (char*)AbufV;

    const int tid  = threadIdx.x;
    const int wid  = tid >> 6;
    const int lane = tid & 63;
    const int lo   = lane & 15;
    const int hi   = lane >> 4;

    // --- W1 B-fragments in registers: wave wid owns columns [64*wid, 64*wid+64) ---
    bf16x8 wfrag[4][4];                        // [ki][ni]
    float  b1v[4], w2v[4];
    #pragma unroll
    for (int ni = 0; ni < 4; ++ni) {
        int n = 64 * wid + 16 * ni + lo;
        b1v[ni] = b1[n];
        w2v[ni] = w2[n];
        #pragma unroll
        for (int ki = 0; ki < 4; ++ki) {
            bf16x8 f;
            #pragma unroll
            for (int e = 0; e < 8; ++e) {
                int d = 32 * ki + 8 * hi + e;
                f[e] = (short)f2bf(W1[d * N_SZ + n]);
            }
            wfrag[ki][ni] = f;
        }
    }

    const int t0 = blockIdx.x * TPB;
    for (int t = t0; t < t0 + TPB; ++t) {
        __syncthreads();   // protects apart (read last iter) before epilogue rewrites

        // ---- construct A tile: 64 rows x 128 bf16, swizzled ----
        {
            const int row = tid >> 2, seg = tid & 3;
            const int rg  = t * BM + row;
            const int ih  = history[rg];
            const int it  = target[rg / H_SZ];
            const float* hp = eh + (size_t)ih * D_SZ + seg * 32;
            const float* tp = et + (size_t)it * D_SZ + seg * 32;
            float xv[32];
            float s = 0.f;
            #pragma unroll
            for (int j = 0; j < 8; ++j) {
                f32x4 hv = *(const f32x4*)(hp + 4 * j);
                f32x4 tv = *(const f32x4*)(tp + 4 * j);
                #pragma unroll
                for (int q = 0; q < 4; ++q) {
                    float x = hv[q] * tv[q];
                    xv[4 * j + q] = x;
                    s += x;
                }
            }
            s += __shfl_xor(s, 1);
            s += __shfl_xor(s, 2);
            if (seg == 0) dotd_out[rg] = s;

            const unsigned sw = (unsigned)((row & 7) << 4);
            char* rbase = Abuf + row * 256;
            #pragma unroll
            for (int i = 0; i < 4; ++i) {
                uint4 pk;
                pk.x = (unsigned)f2bf(xv[8*i+0]) | ((unsigned)f2bf(xv[8*i+1]) << 16);
                pk.y = (unsigned)f2bf(xv[8*i+2]) | ((unsigned)f2bf(xv[8*i+3]) << 16);
                pk.z = (unsigned)f2bf(xv[8*i+4]) | ((unsigned)f2bf(xv[8*i+5]) << 16);
                pk.w = (unsigned)f2bf(xv[8*i+6]) | ((unsigned)f2bf(xv[8*i+7]) << 16);
                *(uint4*)(rbase + (((unsigned)(64 * seg + 16 * i)) ^ sw)) = pk;
            }
        }
        __syncthreads();

        // ---- MFMA: acc[mi][ni] = A(16mi..)(k) @ W1(k)(64wid+16ni..) ----
        f32x4 acc[4][4];
        #pragma unroll
        for (int mi = 0; mi < 4; ++mi)
            #pragma unroll
            for (int ni = 0; ni < 4; ++ni)
                acc[mi][ni] = f32x4{0.f, 0.f, 0.f, 0.f};

        #pragma unroll
        for (int mi = 0; mi < 4; ++mi) {
            bf16x8 af[4];
            #pragma unroll
            for (int ki = 0; ki < 4; ++ki) {
                int row = 16 * mi + lo;
                unsigned off = ((unsigned)(64 * ki + 16 * hi)) ^ ((unsigned)((row & 7) << 4));
                af[ki] = *(const bf16x8*)(Abuf + row * 256 + off);
            }
            #pragma unroll
            for (int ni = 0; ni < 4; ++ni)
                #pragma unroll
                for (int ki = 0; ki < 4; ++ki)
                    acc[mi][ni] = __builtin_amdgcn_mfma_f32_16x16x32_bf16(
                        af[ki], wfrag[ki][ni], acc[mi][ni], 0, 0, 0);
        }

        // ---- epilogue: relu(+b1) . w2, reduce over this wave's 64 columns ----
        #pragma unroll
        for (int mi = 0; mi < 4; ++mi) {
            #pragma unroll
            for (int reg = 0; reg < 4; ++reg) {
                float v = 0.f;
                #pragma unroll
                for (int ni = 0; ni < 4; ++ni) {
                    float c = acc[mi][ni][reg] + b1v[ni];
                    v += fmaxf(c, 0.f) * w2v[ni];
                }
                v += __shfl_xor(v, 1);
                v += __shfl_xor(v, 2);
                v += __shfl_xor(v, 4);
                v += __shfl_xor(v, 8);
                if (lo == 0) apart[wid][16 * mi + 4 * hi + reg] = v;
            }
        }
        __syncthreads();

        if (tid < BM) {
            float a = apart[0][tid] + apart[1][tid] + apart[2][tid] + apart[3][tid];
            a_out[t * BM + tid] = a;
        }
    }
}

// Kernel B: per-b masked exp, beta=0.5 power norm, weighted dot, sigmoid
__global__ __launch_bounds__(64) void nais_finish(
    const int* __restrict__ history, const int* __restrict__ target,
    const float* __restrict__ a_in, const float* __restrict__ dotd_in,
    float* __restrict__ out)
{
    const int b    = blockIdx.x;
    const int lane = threadIdx.x;
    const int tgt  = target[b];
    float s1 = 0.f, s2 = 0.f;
    for (int h = lane; h < H_SZ; h += 64) {
        int rg = b * H_SZ + h;
        float e = (history[rg] != tgt) ? __expf(a_in[rg]) : 0.f;
        s1 += e;
        s2 += e * dotd_in[rg];
    }
    #pragma unroll
    for (int o = 1; o < 64; o <<= 1) {
        s1 += __shfl_xor(s1, o);
        s2 += __shfl_xor(s2, o);
    }
    if (lane == 0) {
        float pred = s2 / sqrtf(s1);   // sum^beta with beta=0.5
        out[b] = 1.f / (1.f + __expf(-pred));
    }
}

extern "C" void kernel_launch(void* const* d_in, const int* in_sizes, int n_in,
                              void* d_out, int out_size, void* d_ws, size_t ws_size,
                              hipStream_t stream) {
    const int*   history = (const int*)d_in[0];
    const int*   target  = (const int*)d_in[1];
    const float* eh      = (const float*)d_in[2];
    const float* et      = (const float*)d_in[3];
    const float* W1      = (const float*)d_in[4];
    const float* b1      = (const float*)d_in[5];
    const float* w2      = (const float*)d_in[6];
    float* out = (float*)d_out;

    float* a_ws    = (float*)d_ws;
    float* dotd_ws = a_ws + ROWS;

    nais_main<<<NBLK, 256, 0, stream>>>(history, target, eh, et, W1, b1, w2, a_ws, dotd_ws);
    nais_finish<<<B_SZ, 64, 0, stream>>>(history, target, a_ws, dotd_ws, out);
}

// Round 2
// 147.009 us; speedup vs baseline: 1.2927x; 1.2927x over previous
//
#include <hip/hip_runtime.h>

#define B_SZ   4096
#define H_SZ   200
#define D_SZ   128
#define N_SZ   256
#define ROWS   (B_SZ * H_SZ)      // 819200
#define BM     64
#define TPB    25                 // tiles per block
#define NBLK   512                // NBLK*TPB*BM == ROWS; each block = 8 whole b-groups
#define BPB    8                  // b's per block (TPB*BM / H_SZ)

typedef __attribute__((ext_vector_type(8))) short bf16x8;
typedef __attribute__((ext_vector_type(4))) float f32x4;

__device__ __forceinline__ unsigned short f2bf(float f) {
    unsigned u = __builtin_bit_cast(unsigned, f);
    u += 0x7FFFu + ((u >> 16) & 1u);
    return (unsigned short)(u >> 16);
}
__device__ __forceinline__ float bflo(unsigned d) {
    return __builtin_bit_cast(float, d << 16);
}
__device__ __forceinline__ float bfhi(unsigned d) {
    return __builtin_bit_cast(float, d & 0xFFFF0000u);
}
__device__ __forceinline__ unsigned packtr(float a, float b) {  // truncating bf16 pack
    return (__builtin_bit_cast(unsigned, a) >> 16) |
           (__builtin_bit_cast(unsigned, b) & 0xFFFF0000u);
}

// Kernel 0: embed_history f32 -> bf16 (RNE), 8 elems/thread
__global__ __launch_bounds__(256) void cvt_eh(const float* __restrict__ src,
                                              uint4* __restrict__ dst, int n8) {
    int i = blockIdx.x * 256 + threadIdx.x;
    if (i >= n8) return;
    const f32x4* p = (const f32x4*)src + (size_t)i * 2;
    f32x4 a = p[0], b = p[1];
    uint4 o;
    o.x = (unsigned)f2bf(a[0]) | ((unsigned)f2bf(a[1]) << 16);
    o.y = (unsigned)f2bf(a[2]) | ((unsigned)f2bf(a[3]) << 16);
    o.z = (unsigned)f2bf(b[0]) | ((unsigned)f2bf(b[1]) << 16);
    o.w = (unsigned)f2bf(b[2]) | ((unsigned)f2bf(b[3]) << 16);
    dst[i] = o;
}

// Main kernel: 512 threads = 8 waves. Wave w owns N-cols [32w, 32w+32).
// Construct: thread = (row = tid>>3, seg = tid&7), 16 elems each.
// Block processes 25 tiles of 64 rows = 8 complete b-groups; finish fused.
__global__ __launch_bounds__(512, 4) void nais_main(
    const int* __restrict__ history, const int* __restrict__ target,
    const uint4* __restrict__ eh16, const float* __restrict__ et,
    const float* __restrict__ W1, const float* __restrict__ b1,
    const float* __restrict__ w2, float* __restrict__ out)
{
    __shared__ uint4 AbufV[BM * 256 / 16];          // 16 KB swizzled [64][128] bf16
    __shared__ float apart[8][BM];                  // 2 KB
    __shared__ float a_lds[TPB * BM];               // 6.4 KB
    __shared__ float dotd_lds[TPB * BM];            // 6.4 KB
    __shared__ unsigned char mask_lds[TPB * BM];    // 1.6 KB
    __shared__ float tgt_e[BPB][D_SZ];              // 4 KB
    __shared__ int   tgt_i[BPB];
    char* Abuf = (char*)AbufV;

    const int tid  = threadIdx.x;
    const int wid  = tid >> 6;
    const int lane = tid & 63;
    const int lo   = lane & 15;
    const int hi   = lane >> 4;
    const int row  = tid >> 3;
    const int seg  = tid & 7;
    const int blk  = blockIdx.x;

    if (tid < BPB) tgt_i[tid] = target[blk * BPB + tid];
    __syncthreads();
    {   // preload the 8 target-embedding rows (f32) into LDS
        const int w8 = tid >> 6, j = (tid & 63) * 2;
        const float* src = et + (size_t)tgt_i[w8] * D_SZ + j;
        tgt_e[w8][j]     = src[0];
        tgt_e[w8][j + 1] = src[1];
    }

    // W1 B-fragments: wave wid owns cols [32*wid, 32*wid+32)
    bf16x8 wfrag[4][2];
    float  b1v[2], w2v[2];
    #pragma unroll
    for (int ni = 0; ni < 2; ++ni) {
        int n = 32 * wid + 16 * ni + lo;
        b1v[ni] = b1[n];
        w2v[ni] = w2[n];
        #pragma unroll
        for (int ki = 0; ki < 4; ++ki) {
            bf16x8 f;
            #pragma unroll
            for (int e = 0; e < 8; ++e)
                f[e] = (short)f2bf(W1[(32 * ki + 8 * hi + e) * N_SZ + n]);
            wfrag[ki][ni] = f;
        }
    }

    // index + gather pipeline prologue
    const int* hrow = history + blk * (TPB * BM) + row;
    int ih_cur = hrow[0];
    int ih_nxt = hrow[BM];
    uint4 hq0, hq1;
    {
        const uint4* p = eh16 + (size_t)ih_cur * 16 + seg * 2;
        hq0 = p[0]; hq1 = p[1];
    }
    __syncthreads();   // tgt_e ready

    for (int t = 0; t < TPB; ++t) {
        const int bl = (t * BM + row) / H_SZ;    // local b index 0..7

        // ---- products (bf16 h  x  f32 t from LDS), dotd, pack ----
        const float* tp = &tgt_e[bl][seg * 16];
        f32x4 t0 = *(const f32x4*)(tp);
        f32x4 t1 = *(const f32x4*)(tp + 4);
        f32x4 t2 = *(const f32x4*)(tp + 8);
        f32x4 t3 = *(const f32x4*)(tp + 12);
        unsigned hd[8] = {hq0.x, hq0.y, hq0.z, hq0.w, hq1.x, hq1.y, hq1.z, hq1.w};
        float tv[16]   = {t0[0], t0[1], t0[2], t0[3], t1[0], t1[1], t1[2], t1[3],
                          t2[0], t2[1], t2[2], t2[3], t3[0], t3[1], t3[2], t3[3]};
        unsigned xp[8];
        float s = 0.f;
        #pragma unroll
        for (int j = 0; j < 8; ++j) {
            float x0 = bflo(hd[j]) * tv[2 * j];
            float x1 = bfhi(hd[j]) * tv[2 * j + 1];
            s += x0 + x1;
            xp[j] = packtr(x0, x1);
        }
        s += __shfl_xor(s, 1);
        s += __shfl_xor(s, 2);
        s += __shfl_xor(s, 4);
        if (seg == 0) {
            dotd_lds[t * BM + row] = s;
            mask_lds[t * BM + row] = (ih_cur != tgt_i[bl]) ? 1 : 0;
        }
        {
            const unsigned sw = (unsigned)((row & 7) << 4);
            char* rbase = Abuf + row * 256;
            *(uint4*)(rbase + (((unsigned)(32 * seg)) ^ sw))      = uint4{xp[0], xp[1], xp[2], xp[3]};
            *(uint4*)(rbase + (((unsigned)(32 * seg + 16)) ^ sw)) = uint4{xp[4], xp[5], xp[6], xp[7]};
        }
        __syncthreads();   // [B1] A-tile ready

        // ---- issue next tile's gathers (hide under MFMA) ----
        if (t + 1 < TPB) {
            ih_cur = ih_nxt;
            if (t + 2 < TPB) ih_nxt = hrow[(t + 2) * BM];
            const uint4* p = eh16 + (size_t)ih_cur * 16 + seg * 2;
            hq0 = p[0]; hq1 = p[1];
        }

        // ---- MFMA ----
        f32x4 acc[4][2];
        #pragma unroll
        for (int mi = 0; mi < 4; ++mi)
            #pragma unroll
            for (int ni = 0; ni < 2; ++ni)
                acc[mi][ni] = f32x4{0.f, 0.f, 0.f, 0.f};

        #pragma unroll
        for (int mi = 0; mi < 4; ++mi) {
            bf16x8 af[4];
            const int rr = 16 * mi + lo;
            #pragma unroll
            for (int ki = 0; ki < 4; ++ki) {
                unsigned off = ((unsigned)(64 * ki + 16 * hi)) ^ ((unsigned)((rr & 7) << 4));
                af[ki] = *(const bf16x8*)(Abuf + rr * 256 + off);
            }
            #pragma unroll
            for (int ni = 0; ni < 2; ++ni)
                #pragma unroll
                for (int ki = 0; ki < 4; ++ki)
                    acc[mi][ni] = __builtin_amdgcn_mfma_f32_16x16x32_bf16(
                        af[ki], wfrag[ki][ni], acc[mi][ni], 0, 0, 0);
        }

        // ---- epilogue: relu(+b1) . w2 over this wave's 32 cols ----
        #pragma unroll
        for (int mi = 0; mi < 4; ++mi) {
            #pragma unroll
            for (int reg = 0; reg < 4; ++reg) {
                float v = 0.f;
                #pragma unroll
                for (int ni = 0; ni < 2; ++ni) {
                    float c = acc[mi][ni][reg] + b1v[ni];
                    v += fmaxf(c, 0.f) * w2v[ni];
                }
                v += __shfl_xor(v, 1);
                v += __shfl_xor(v, 2);
                v += __shfl_xor(v, 4);
                v += __shfl_xor(v, 8);
                if (lo == 0) apart[wid][16 * mi + 4 * hi + reg] = v;
            }
        }
        __syncthreads();   // [B2] apart ready; MFMA reads of Abuf done

        if (tid < BM) {
            float a = apart[0][tid];
            #pragma unroll
            for (int w = 1; w < 8; ++w) a += apart[w][tid];
            a_lds[t * BM + tid] = a;
        }
    }
    __syncthreads();

    // ---- fused finish: wave w handles b-group w ----
    {
        float s1 = 0.f, s2 = 0.f;
        for (int h = lane; h < H_SZ; h += 64) {
            int r = wid * H_SZ + h;
            float e = mask_lds[r] ? __expf(a_lds[r]) : 0.f;
            s1 += e;
            s2 += e * dotd_lds[r];
        }
        #pragma unroll
        for (int o = 1; o < 64; o <<= 1) {
            s1 += __shfl_xor(s1, o);
            s2 += __shfl_xor(s2, o);
        }
        if (lane == 0) {
            float pred = s2 / sqrtf(s1);
            out[blk * BPB + wid] = 1.f / (1.f + __expf(-pred));
        }
    }
}

extern "C" void kernel_launch(void* const* d_in, const int* in_sizes, int n_in,
                              void* d_out, int out_size, void* d_ws, size_t ws_size,
                              hipStream_t stream) {
    const int*   history = (const int*)d_in[0];
    const int*   target  = (const int*)d_in[1];
    const float* eh      = (const float*)d_in[2];
    const float* et      = (const float*)d_in[3];
    const float* W1      = (const float*)d_in[4];
    const float* b1      = (const float*)d_in[5];
    const float* w2      = (const float*)d_in[6];
    float* out = (float*)d_out;

    uint4* eh16 = (uint4*)d_ws;                      // 100000*128*2 B = 25.6 MB
    const int n8 = 100000 * D_SZ / 8;                // 1.6M uint4s

    cvt_eh<<<(n8 + 255) / 256, 256, 0, stream>>>(eh, eh16, n8);
    nais_main<<<NBLK, 512, 0, stream>>>(history, target, eh16, et, W1, b1, w2, out);
}